// Round 13
// baseline (564.096 us; speedup 1.0000x reference)
//
#include <hip/hip_runtime.h>

#define NB 256
#define NT 1024
#define NC 128
#define ND 64
#define SP 16
#define NSL 32
#define NJ 68
#define PXW 196   // padded partials row (f32 units)
#define PHW 72    // padded pack row (f16 units)

typedef _Float16 f16x8 __attribute__((ext_vector_type(8)));
typedef float f32x4 __attribute__((ext_vector_type(4)));

__device__ __forceinline__ float fexp2(float x){
#if __has_builtin(__builtin_amdgcn_exp2f)
  return __builtin_amdgcn_exp2f(x);
#else
  return exp2f(x);
#endif
}
__device__ __forceinline__ float frcp_(float x){
#if __has_builtin(__builtin_amdgcn_rcpf)
  return __builtin_amdgcn_rcpf(x);
#else
  return 1.0f / x;
#endif
}
__device__ __forceinline__ float sigmoid_f(float x){
  return frcp_(1.0f + fexp2(-1.4426950408889634f * x));
}
__device__ __forceinline__ float tanh_f(float x){
  return 1.0f - 2.0f * frcp_(fexp2(2.8853900817779268f * x) + 1.0f);
}
// exp(CLAMP*0.636*atan(s/CLAMP)) with CLAMP=5 -> exp(3.18*atan(0.2*s))
__device__ __forceinline__ float e_func(float s){
  float u = 0.2f * s;
  float au = fabsf(u);
  bool inv = au > 1.0f;
  float v = inv ? frcp_(au) : au;
  float v2 = v * v;
  float pp = -0.0117212f;
  pp = pp * v2 + 0.05265332f;
  pp = pp * v2 - 0.11643287f;
  pp = pp * v2 + 0.19354346f;
  pp = pp * v2 - 0.33262347f;
  pp = pp * v2 + 0.99997726f;
  float at = pp * v;
  if (inv) at = 1.5707963267948966f - at;
  at = __builtin_copysignf(at, u);
  return fexp2(4.5877702301963f * at); // 3.18 * log2(e) * atan
}

// LDS-only barrier (single asm blob)
#define BAR() asm volatile("s_waitcnt lgkmcnt(0)\n\ts_barrier" ::: "memory")

// B-fragment: lane l holds B[k=32*ks+8*(l>>4)+j][c=tile*16+(l&15)]
__device__ __forceinline__ f16x8 bld(const float* __restrict__ W, int ldw,
                                     int ks, int tile, int lane){
  f16x8 v;
  const int kb = ks*32 + 8*(lane>>4);
  const int c  = tile*16 + (lane&15);
  #pragma unroll
  for (int j = 0; j < 8; ++j) v[j] = (_Float16)W[(kb + j)*ldw + c];
  return v;
}
// A-fragment from padded f16 ring: rows = time steps. lane l -> row t0+(l&15),
// k = 8*(l>>4)+j + 32*ks. Row stride PHW f16.
__device__ __forceinline__ f16x8 ldafb(const _Float16* ring, int t0, int lane, int ks){
  return *reinterpret_cast<const f16x8*>(
      reinterpret_cast<const char*>(ring)
      + (((t0 & (NSL-1)) + (lane & 15)) * (PHW*2)) + 16*(lane>>4) + 64*ks);
}
__device__ __forceinline__ float sel4(float a0, float a1, float a2, float a3, int lane){
  float t01 = (lane & 16) ? a1 : a0;
  float t23 = (lane & 16) ? a3 : a2;
  return (lane & 32) ? t23 : t01;
}
#define MFMA16(acc, a, bfr) acc = __builtin_amdgcn_mfma_f32_16x16x32_f16(a, bfr, acc, 0, 0, 0)

// lane^1 neighbor via DPP quad_perm [1,0,3,2] (VALU, no LDS)
__device__ __forceinline__ float dpp_xor1(float v){
  int r = __builtin_amdgcn_update_dpp(0, __builtin_bit_cast(int, v),
                                      0xB1, 0xF, 0xF, true);
  return __builtin_bit_cast(float, r);
}
// In-register redistribution: h (f32, lane i = unit i) -> A-frags (row-replicated)
__device__ __forceinline__ void redist(float h, int lane, const int* addrs,
                                       f16x8* a0, f16x8* a1){
  float hsw = dpp_xor1(h);
  float lo = (lane & 1) ? hsw : h;
  float hp = (lane & 1) ? h : hsw;
  int pd = __builtin_bit_cast(int, __builtin_amdgcn_cvt_pkrtz(lo, hp));
  int d[8];
  #pragma unroll
  for (int q = 0; q < 8; ++q) d[q] = __builtin_amdgcn_ds_bpermute(addrs[q], pd);
  union { int u[4]; f16x8 v; } u0, u1;
  u0.u[0]=d[0]; u0.u[1]=d[1]; u0.u[2]=d[2]; u0.u[3]=d[3];
  u1.u[0]=d[4]; u1.u[1]=d[5]; u1.u[2]=d[6]; u1.u[3]=d[7];
  *a0 = u0.v; *a1 = u1.v;
}
__device__ __forceinline__ f16x8 packx8(float4 u, float4 v){
  f16x8 r;
  r[0]=(_Float16)u.x; r[1]=(_Float16)u.y; r[2]=(_Float16)u.z; r[3]=(_Float16)u.w;
  r[4]=(_Float16)v.x; r[5]=(_Float16)v.y; r[6]=(_Float16)v.z; r[7]=(_Float16)v.w;
  return r;
}

// 8 waves (512 thr), SIMD = w%4.
// w0=A2(gx2)@16J [S0]      w1=C2(gy1)@16(J-3) [S1]
// w2=A1(h2 rec)@16(J-1)[S2]  w6=C1(h1 rec)@16(J-4) [S2]  <- co-located chains
// w4=B(Wo2+y1)@16(J-2)[S0] w5=D(Wo1+y2)@16(J-5) [S1]   w3,w7 idle [S3]
__global__ __launch_bounds__(512, 1)
void glow_gru_kernel(const float* __restrict__ x,
                     const float* __restrict__ Wx1, const float* __restrict__ Wh1,
                     const float* __restrict__ bx1, const float* __restrict__ bh1,
                     const float* __restrict__ Wo1, const float* __restrict__ bo1,
                     const float* __restrict__ Wx2, const float* __restrict__ Wh2,
                     const float* __restrict__ bx2, const float* __restrict__ bh2,
                     const float* __restrict__ Wo2, const float* __restrict__ bo2,
                     float* __restrict__ out)
{
  __shared__ __align__(16) _Float16 h2p[NSL][PHW]; // h2(t) packs (A1 -> B)
  __shared__ __align__(16) _Float16 y1p[NSL][PHW]; // y1(t) packs (B -> C2)
  __shared__ __align__(16) _Float16 h1p[NSL][PHW]; // h1(t) packs (C1 -> D)
  __shared__ float px2[NSL][PXW];                  // gx2 partials (A2 -> A1)
  __shared__ float py1[NSL][PXW];                  // gy1 partials (C2 -> C1)

  const int l = threadIdx.x;
  const int w = l >> 6;
  const int i = l & 63;
  const int b = blockIdx.x;
  const long xbase = (long)b * NT * NC;

  if (w == 0){
    // ===== A2: gx2[16][192] = X2[16][64] @ Wx2 — batched, A-frag from global =====
    f16x8 bf[12][2];
    #pragma unroll
    for (int t = 0; t < 12; ++t){ bf[t][0] = bld(Wx2,192,0,t,i); bf[t][1] = bld(Wx2,192,1,t,i); }
    const float* pxA = x + xbase + 64 + (long)(i & 15)*NC + 8*(i >> 4);
    __syncthreads();
    for (int J = 0; J <= NJ; ++J){
      const int t0 = SP*J;
      if (t0 < NT){
        const float* base = pxA + (long)t0*NC;
        float4 u0 = *(const float4*)(base);
        float4 u1 = *(const float4*)(base + 4);
        float4 v0 = *(const float4*)(base + 32);
        float4 v1 = *(const float4*)(base + 36);
        f16x8 a0 = packx8(u0, u1);
        f16x8 a1 = packx8(v0, v1);
        f32x4 zz = {0.f,0.f,0.f,0.f};
        f32x4 acc[12];
        #pragma unroll
        for (int t2 = 0; t2 < 12; ++t2){
          acc[t2] = zz;
          MFMA16(acc[t2], a0, bf[t2][0]);
          MFMA16(acc[t2], a1, bf[t2][1]);
        }
        const int rb = (t0 + 4*(i>>4)) & (NSL-1);
        #pragma unroll
        for (int t2 = 0; t2 < 12; ++t2){
          #pragma unroll
          for (int rg = 0; rg < 4; ++rg)
            px2[rb + rg][t2*16 + (i&15)] = acc[t2][rg];
        }
      }
      BAR();
    }
  } else if (w == 1){
    // ===== C2: gy1[16][192] = Y1[16][64] @ Wx1 — batched, A-frag from y1p ring =====
    f16x8 bf[12][2];
    #pragma unroll
    for (int t = 0; t < 12; ++t){ bf[t][0] = bld(Wx1,192,0,t,i); bf[t][1] = bld(Wx1,192,1,t,i); }
    __syncthreads();
    for (int J = 0; J <= NJ; ++J){
      const int t0 = SP*(J-3);
      if (t0 >= 0 && t0 < NT){
        f16x8 a0 = ldafb(&y1p[0][0], t0, i, 0);
        f16x8 a1 = ldafb(&y1p[0][0], t0, i, 1);
        f32x4 zz = {0.f,0.f,0.f,0.f};
        f32x4 acc[12];
        #pragma unroll
        for (int t2 = 0; t2 < 12; ++t2){
          acc[t2] = zz;
          MFMA16(acc[t2], a0, bf[t2][0]);
          MFMA16(acc[t2], a1, bf[t2][1]);
        }
        const int rb = (t0 + 4*(i>>4)) & (NSL-1);
        #pragma unroll
        for (int t2 = 0; t2 < 12; ++t2){
          #pragma unroll
          for (int rg = 0; rg < 4; ++rg)
            py1[rb + rg][t2*16 + (i&15)] = acc[t2][rg];
        }
      }
      BAR();
    }
  } else if (w == 2 || w == 6){
    // ===== A1 / C1: GRU recurrence, 16 sequential steps — co-located on SIMD2 =====
    const bool isA = (w == 2);
    const float* WH = isA ? Wh2 : Wh1;
    const float* bx = isA ? bx2 : bx1;
    const float* bh = isA ? bh2 : bh1;
    _Float16 (*hr)[PHW] = isA ? h2p : h1p;
    float (*pr)[PXW]    = isA ? px2 : py1;
    const int lag = isA ? 1 : 4;
    f16x8 bf[12][2];
    #pragma unroll
    for (int t = 0; t < 12; ++t){ bf[t][0] = bld(WH,192,0,t,i); bf[t][1] = bld(WH,192,1,t,i); }
    int addrs[8];
    #pragma unroll
    for (int q = 0; q < 8; ++q) addrs[q] = 8*(16*(q>>2) + 4*(i>>4) + (q&3));
    const float b0 = bx[i] + bh[i];
    const float b1 = bx[64+i] + bh[64+i];
    const float b2v = bx[128+i], b3v = bh[128+i];
    float h = 0.f;
    __syncthreads();
    for (int J = 0; J <= NJ; ++J){
      const int t0 = SP*(J - lag);
      if (t0 >= 0 && t0 < NT){
        float rxs[SP], zxs[SP], nxs[SP];
        #pragma unroll
        for (int s = 0; s < SP; ++s){
          rxs[s] = pr[(t0+s)&(NSL-1)][i];
          zxs[s] = pr[(t0+s)&(NSL-1)][64+i];
          nxs[s] = pr[(t0+s)&(NSL-1)][128+i];
        }
        #pragma unroll
        for (int s = 0; s < SP; ++s){
          const int t = t0 + s;
          f16x8 a0, a1;
          redist(h, i, addrs, &a0, &a1);
          f32x4 accA[12], accB[12];
          f32x4 zz = {0.f,0.f,0.f,0.f};
          #pragma unroll
          for (int t2 = 0; t2 < 12; ++t2){ accA[t2] = zz; MFMA16(accA[t2], a0, bf[t2][0]); }
          #pragma unroll
          for (int t2 = 0; t2 < 12; ++t2){ accB[t2] = zz; MFMA16(accB[t2], a1, bf[t2][1]); }
          float rh = sel4(accA[0][0]+accB[0][0], accA[1][0]+accB[1][0],
                          accA[2][0]+accB[2][0], accA[3][0]+accB[3][0], i);
          float r = sigmoid_f(rxs[s] + rh + b0);
          float zh = sel4(accA[4][0]+accB[4][0], accA[5][0]+accB[5][0],
                          accA[6][0]+accB[6][0], accA[7][0]+accB[7][0], i);
          float z = sigmoid_f(zxs[s] + zh + b1);
          float nh = sel4(accA[8][0]+accB[8][0], accA[9][0]+accB[9][0],
                          accA[10][0]+accB[10][0], accA[11][0]+accB[11][0], i);
          float nn = tanh_f(nxs[s] + b2v + r*(nh + b3v));
          h = (1.f - z)*nn + z*h;
          hr[t&(NSL-1)][i] = (_Float16)h;   // publish for B/D
        }
      }
      BAR();
    }
  } else if (w == 4 || w == 5){
    // ===== B / D: output heads, batched 16 steps, x prefetched 1 superphase ahead =====
    const bool isB = (w == 4);
    const float* WO = isB ? Wo2 : Wo1;
    const float* bo = isB ? bo2 : bo1;
    _Float16 (*hr)[PHW] = isB ? h2p : h1p;
    const int lag  = isB ? 2 : 5;
    const int xoff = isB ? 0 : 64;
    f16x8 bf[8][2];
    #pragma unroll
    for (int t = 0; t < 8; ++t){ bf[t][0] = bld(WO,128,0,t,i); bf[t][1] = bld(WO,128,1,t,i); }
    const int c = i & 15;
    float bS[4], bT[4];
    #pragma unroll
    for (int t2 = 0; t2 < 4; ++t2){
      bS[t2] = bo[t2*16 + c];
      bT[t2] = bo[64 + t2*16 + c];
    }
    float xg[4][4], xn[4][4];
    __syncthreads();
    for (int J = 0; J <= NJ; ++J){
      const int t0 = SP*(J - lag);
      // prefetch x cells for NEXT superphase's t0 (t0n = t0 + SP)
      const int t0n = t0 + SP;
      if (t0n >= 0 && t0n < NT){
        #pragma unroll
        for (int t2 = 0; t2 < 4; ++t2){
          #pragma unroll
          for (int rg = 0; rg < 4; ++rg){
            const int t = t0n + 4*(i>>4) + rg;
            xn[t2][rg] = x[xbase + (long)t*NC + xoff + t2*16 + c];
          }
        }
      }
      if (t0 == 0){
        // first active superphase: load own x cells directly (not prefetched)
        #pragma unroll
        for (int t2 = 0; t2 < 4; ++t2){
          #pragma unroll
          for (int rg = 0; rg < 4; ++rg){
            const int t = t0 + 4*(i>>4) + rg;
            xg[t2][rg] = x[xbase + (long)t*NC + xoff + t2*16 + c];
          }
        }
      }
      if (t0 >= 0 && t0 < NT){
        f16x8 a0 = ldafb(&hr[0][0], t0, i, 0);
        f16x8 a1 = ldafb(&hr[0][0], t0, i, 1);
        f32x4 zz = {0.f,0.f,0.f,0.f};
        f32x4 acc[8];
        #pragma unroll
        for (int t2 = 0; t2 < 8; ++t2){
          acc[t2] = zz;
          MFMA16(acc[t2], a0, bf[t2][0]);
          MFMA16(acc[t2], a1, bf[t2][1]);
        }
        #pragma unroll
        for (int t2 = 0; t2 < 4; ++t2){
          #pragma unroll
          for (int rg = 0; rg < 4; ++rg){
            const int t = t0 + 4*(i>>4) + rg;
            float y = e_func(acc[t2][rg] + bS[t2]) * xg[t2][rg] + (acc[t2+4][rg] + bT[t2]);
            out[xbase + (long)t*NC + xoff + t2*16 + c] = y;
            if (isB) y1p[t & (NSL-1)][t2*16 + c] = (_Float16)y;
          }
        }
      }
      #pragma unroll
      for (int t2 = 0; t2 < 4; ++t2)
        #pragma unroll
        for (int rg = 0; rg < 4; ++rg) xg[t2][rg] = xn[t2][rg];
      BAR();
    }
  } else {
    // ===== w3 / w7: idle companions on S3 (barrier keepers) =====
    __syncthreads();
    for (int J = 0; J <= NJ; ++J){ BAR(); }
  }
}

extern "C" void kernel_launch(void* const* d_in, const int* in_sizes, int n_in,
                              void* d_out, int out_size, void* d_ws, size_t ws_size,
                              hipStream_t stream) {
  const float* x   = (const float*)d_in[0];
  const float* Wx1 = (const float*)d_in[1];
  const float* Wh1 = (const float*)d_in[2];
  const float* bx1 = (const float*)d_in[3];
  const float* bh1 = (const float*)d_in[4];
  const float* Wo1 = (const float*)d_in[5];
  const float* bo1 = (const float*)d_in[6];
  const float* Wx2 = (const float*)d_in[7];
  const float* Wh2 = (const float*)d_in[8];
  const float* bx2 = (const float*)d_in[9];
  const float* bh2 = (const float*)d_in[10];
  const float* Wo2 = (const float*)d_in[11];
  const float* bo2 = (const float*)d_in[12];
  float* out = (float*)d_out;

  hipLaunchKernelGGL(glow_gru_kernel, dim3(NB), dim3(512), 0, stream,
                     x, Wx1, Wh1, bx1, bh1, Wo1, bo1,
                     Wx2, Wh2, bx2, bh2, Wo2, bo2, out);
}

// Round 14
// 354.777 us; speedup vs baseline: 1.5900x; 1.5900x over previous
//
#include <hip/hip_runtime.h>

#define NB 256
#define NT 1024
#define NC 128
#define ND 64
#define SP 16
#define NSL 32
#define NJ 68
#define PXW 196   // padded partials row (f32 units)
#define PHW 72    // padded pack row (f16 units)

typedef _Float16 f16x8 __attribute__((ext_vector_type(8)));
typedef float f32x4 __attribute__((ext_vector_type(4)));
typedef _Float16 f16x2_t __attribute__((ext_vector_type(2)));

__device__ __forceinline__ float fexp2(float x){
#if __has_builtin(__builtin_amdgcn_exp2f)
  return __builtin_amdgcn_exp2f(x);
#else
  return exp2f(x);
#endif
}
__device__ __forceinline__ float frcp_(float x){
#if __has_builtin(__builtin_amdgcn_rcpf)
  return __builtin_amdgcn_rcpf(x);
#else
  return 1.0f / x;
#endif
}
__device__ __forceinline__ float sigmoid_f(float x){
  return frcp_(1.0f + fexp2(-1.4426950408889634f * x));
}
__device__ __forceinline__ float tanh_f(float x){
  return 1.0f - 2.0f * frcp_(fexp2(2.8853900817779268f * x) + 1.0f);
}
// exp(CLAMP*0.636*atan(s/CLAMP)) with CLAMP=5 -> exp(3.18*atan(0.2*s))
__device__ __forceinline__ float e_func(float s){
  float u = 0.2f * s;
  float au = fabsf(u);
  bool inv = au > 1.0f;
  float v = inv ? frcp_(au) : au;
  float v2 = v * v;
  float pp = -0.0117212f;
  pp = pp * v2 + 0.05265332f;
  pp = pp * v2 - 0.11643287f;
  pp = pp * v2 + 0.19354346f;
  pp = pp * v2 - 0.33262347f;
  pp = pp * v2 + 0.99997726f;
  float at = pp * v;
  if (inv) at = 1.5707963267948966f - at;
  at = __builtin_copysignf(at, u);
  return fexp2(4.5877702301963f * at); // 3.18 * log2(e) * atan
}

// LDS-only barrier (single asm blob)
#define BAR() asm volatile("s_waitcnt lgkmcnt(0)\n\ts_barrier" ::: "memory")

// B-fragment: lane l holds B[k=32*ks+8*(l>>4)+j][c=tile*16+(l&15)]
__device__ __forceinline__ f16x8 bld(const float* __restrict__ W, int ldw,
                                     int ks, int tile, int lane){
  f16x8 v;
  const int kb = ks*32 + 8*(lane>>4);
  const int c  = tile*16 + (lane&15);
  #pragma unroll
  for (int j = 0; j < 8; ++j) v[j] = (_Float16)W[(kb + j)*ldw + c];
  return v;
}
// A-fragment from padded f16 ring: rows = time steps. lane l -> row t0+(l&15),
// k = 8*(l>>4)+j + 32*ks. Row stride PHW f16.
__device__ __forceinline__ f16x8 ldafb(const _Float16* ring, int t0, int lane, int ks){
  return *reinterpret_cast<const f16x8*>(
      reinterpret_cast<const char*>(ring)
      + (((t0 & (NSL-1)) + (lane & 15)) * (PHW*2)) + 16*(lane>>4) + 64*ks);
}
#define MFMA16(acc, a, bfr) acc = __builtin_amdgcn_mfma_f32_16x16x32_f16(a, bfr, acc, 0, 0, 0)

// f16-pair dot with f32 accumulate
__device__ __forceinline__ float fdot2u(unsigned a, unsigned b, float c){
#if __has_builtin(__builtin_amdgcn_fdot2)
  return __builtin_amdgcn_fdot2(__builtin_bit_cast(f16x2_t, a), __builtin_bit_cast(f16x2_t, b), c, false);
#else
  f16x2_t av = __builtin_bit_cast(f16x2_t, a);
  f16x2_t bv = __builtin_bit_cast(f16x2_t, b);
  return c + (float)av[0]*(float)bv[0] + (float)av[1]*(float)bv[1];
#endif
}
__device__ __forceinline__ unsigned packh(float a, float b){
  union { _Float16 h[2]; unsigned u; } v;
  v.h[0] = (_Float16)a; v.h[1] = (_Float16)b;
  return v.u;
}
// lane^1 neighbor via DPP quad_perm [1,0,3,2] (VALU, no LDS)
__device__ __forceinline__ float dpp_xor1(float v){
  int r = __builtin_amdgcn_update_dpp(0, __builtin_bit_cast(int, v),
                                      0xB1, 0xF, 0xF, true);
  return __builtin_bit_cast(float, r);
}
__device__ __forceinline__ f16x8 packx8(float4 u, float4 v){
  f16x8 r;
  r[0]=(_Float16)u.x; r[1]=(_Float16)u.y; r[2]=(_Float16)u.z; r[3]=(_Float16)u.w;
  r[4]=(_Float16)v.x; r[5]=(_Float16)v.y; r[6]=(_Float16)v.z; r[7]=(_Float16)v.w;
  return r;
}

// 6 waves (384 thr), SIMD = w%4.
// w0=A2(gx2)@16J [S0]   w1=C2(gy1)@16(J-3) [S1]  w2=A1(h2 rec, fdot2) [S2]
// w3=C1(h1 rec, fdot2) [S3]  w4=B(Wo2+y1)@16(J-2) [S0]  w5=D(Wo1+y2)@16(J-5) [S1]
__global__ __launch_bounds__(384, 1)
void glow_gru_kernel(const float* __restrict__ x,
                     const float* __restrict__ Wx1, const float* __restrict__ Wh1,
                     const float* __restrict__ bx1, const float* __restrict__ bh1,
                     const float* __restrict__ Wo1, const float* __restrict__ bo1,
                     const float* __restrict__ Wx2, const float* __restrict__ Wh2,
                     const float* __restrict__ bx2, const float* __restrict__ bh2,
                     const float* __restrict__ Wo2, const float* __restrict__ bo2,
                     float* __restrict__ out)
{
  __shared__ __align__(16) _Float16 h2p[NSL][PHW]; // h2(t) packs (A1 -> B)
  __shared__ __align__(16) _Float16 y1p[NSL][PHW]; // y1(t) packs (B -> C2)
  __shared__ __align__(16) _Float16 h1p[NSL][PHW]; // h1(t) packs (C1 -> D)
  __shared__ float px2[NSL][PXW];                  // gx2 partials (A2 -> A1)
  __shared__ float py1[NSL][PXW];                  // gy1 partials (C2 -> C1)

  const int l = threadIdx.x;
  const int w = l >> 6;
  const int i = l & 63;
  const int b = blockIdx.x;
  const long xbase = (long)b * NT * NC;

  if (w == 0){
    // ===== A2: gx2[16][192] = X2[16][64] @ Wx2 — batched MFMA, A-frag from global =====
    f16x8 bf[12][2];
    #pragma unroll
    for (int t = 0; t < 12; ++t){ bf[t][0] = bld(Wx2,192,0,t,i); bf[t][1] = bld(Wx2,192,1,t,i); }
    const float* pxA = x + xbase + 64 + (long)(i & 15)*NC + 8*(i >> 4);
    __syncthreads();
    for (int J = 0; J <= NJ; ++J){
      const int t0 = SP*J;
      if (t0 < NT){
        const float* base = pxA + (long)t0*NC;
        float4 u0 = *(const float4*)(base);
        float4 u1 = *(const float4*)(base + 4);
        float4 v0 = *(const float4*)(base + 32);
        float4 v1 = *(const float4*)(base + 36);
        f16x8 a0 = packx8(u0, u1);
        f16x8 a1 = packx8(v0, v1);
        f32x4 zz = {0.f,0.f,0.f,0.f};
        f32x4 acc[12];
        #pragma unroll
        for (int t2 = 0; t2 < 12; ++t2){
          acc[t2] = zz;
          MFMA16(acc[t2], a0, bf[t2][0]);
          MFMA16(acc[t2], a1, bf[t2][1]);
        }
        const int rb = (t0 + 4*(i>>4)) & (NSL-1);
        #pragma unroll
        for (int t2 = 0; t2 < 12; ++t2){
          #pragma unroll
          for (int rg = 0; rg < 4; ++rg)
            px2[rb + rg][t2*16 + (i&15)] = acc[t2][rg];
        }
      }
      BAR();
    }
  } else if (w == 1){
    // ===== C2: gy1[16][192] = Y1[16][64] @ Wx1 — batched MFMA, A-frag from y1p ring =====
    f16x8 bf[12][2];
    #pragma unroll
    for (int t = 0; t < 12; ++t){ bf[t][0] = bld(Wx1,192,0,t,i); bf[t][1] = bld(Wx1,192,1,t,i); }
    __syncthreads();
    for (int J = 0; J <= NJ; ++J){
      const int t0 = SP*(J-3);
      if (t0 >= 0 && t0 < NT){
        f16x8 a0 = ldafb(&y1p[0][0], t0, i, 0);
        f16x8 a1 = ldafb(&y1p[0][0], t0, i, 1);
        f32x4 zz = {0.f,0.f,0.f,0.f};
        f32x4 acc[12];
        #pragma unroll
        for (int t2 = 0; t2 < 12; ++t2){
          acc[t2] = zz;
          MFMA16(acc[t2], a0, bf[t2][0]);
          MFMA16(acc[t2], a1, bf[t2][1]);
        }
        const int rb = (t0 + 4*(i>>4)) & (NSL-1);
        #pragma unroll
        for (int t2 = 0; t2 < 12; ++t2){
          #pragma unroll
          for (int rg = 0; rg < 4; ++rg)
            py1[rb + rg][t2*16 + (i&15)] = acc[t2][rg];
        }
      }
      BAR();
    }
  } else if (w == 2 || w == 3){
    // ===== A1 / C1: GRU recurrence via fdot2; h broadcast via DPP+cvt_pk+32 bpermute =====
    const bool isA = (w == 2);
    const float* WH = isA ? Wh2 : Wh1;
    const float* bx = isA ? bx2 : bx1;
    const float* bh = isA ? bh2 : bh1;
    _Float16 (*hr)[PHW] = isA ? h2p : h1p;
    float (*pr)[PXW]    = isA ? px2 : py1;
    const int lag = isA ? 1 : 4;
    // weights: own 3 gate columns, full k=64 as f16 pairs (96 VGPRs)
    unsigned wr[32], wz[32], wn[32];
    #pragma unroll
    for (int k2 = 0; k2 < 32; ++k2){
      wr[k2] = packh(WH[(2*k2)*192 + i],       WH[(2*k2+1)*192 + i]);
      wz[k2] = packh(WH[(2*k2)*192 + 64 + i],  WH[(2*k2+1)*192 + 64 + i]);
      wn[k2] = packh(WH[(2*k2)*192 + 128 + i], WH[(2*k2+1)*192 + 128 + i]);
    }
    int addrs[32];
    #pragma unroll
    for (int q = 0; q < 32; ++q) addrs[q] = 8*q;   // byte addr of lane 2q
    const float b0 = bx[i] + bh[i];
    const float b1 = bx[64+i] + bh[64+i];
    const float b2v = bx[128+i], b3v = bh[128+i];
    float h = 0.f;
    __syncthreads();
    for (int J = 0; J <= NJ; ++J){
      const int t0 = SP*(J - lag);
      if (t0 >= 0 && t0 < NT){
        #pragma unroll
        for (int s = 0; s < SP; ++s){
          const int t = t0 + s;
          // ---- broadcast h to all lanes as 32 packed-f16 dwords ----
          float hsw = dpp_xor1(h);
          float lo = (i & 1) ? hsw : h;
          float hp = (i & 1) ? h : hsw;
          int pk = __builtin_bit_cast(int, __builtin_amdgcn_cvt_pkrtz(lo, hp));
          int hv[32];
          #pragma unroll
          for (int q = 0; q < 32; ++q) hv[q] = __builtin_amdgcn_ds_bpermute(addrs[q], pk);
          // ---- x-side partials (latency overlaps bpermutes) ----
          float rx = pr[t&(NSL-1)][i];
          float zx = pr[t&(NSL-1)][64+i];
          float nx = pr[t&(NSL-1)][128+i];
          // ---- 96 fdot2, 6 accumulator chains ----
          float rh0=0.f, rh1=0.f, zh0=0.f, zh1=0.f, nh0=0.f, nh1=0.f;
          #pragma unroll
          for (int k2 = 0; k2 < 16; ++k2){
            rh0 = fdot2u((unsigned)hv[k2],    wr[k2],    rh0);
            zh0 = fdot2u((unsigned)hv[k2],    wz[k2],    zh0);
            nh0 = fdot2u((unsigned)hv[k2],    wn[k2],    nh0);
            rh1 = fdot2u((unsigned)hv[16+k2], wr[16+k2], rh1);
            zh1 = fdot2u((unsigned)hv[16+k2], wz[16+k2], zh1);
            nh1 = fdot2u((unsigned)hv[16+k2], wn[16+k2], nh1);
          }
          float r = sigmoid_f(rx + rh0 + rh1 + b0);
          float z = sigmoid_f(zx + zh0 + zh1 + b1);
          float nn = tanh_f(nx + b2v + r*(nh0 + nh1 + b3v));
          h = (1.f - z)*nn + z*h;
          hr[t&(NSL-1)][i] = (_Float16)h;   // publish for B/D (off critical path)
        }
      }
      BAR();
    }
  } else {
    // ===== B / D: output heads, batched 16 steps, x prefetched 1 superphase ahead =====
    const bool isB = (w == 4);
    const float* WO = isB ? Wo2 : Wo1;
    const float* bo = isB ? bo2 : bo1;
    _Float16 (*hr)[PHW] = isB ? h2p : h1p;
    const int lag  = isB ? 2 : 5;
    const int xoff = isB ? 0 : 64;
    f16x8 bf[8][2];
    #pragma unroll
    for (int t = 0; t < 8; ++t){ bf[t][0] = bld(WO,128,0,t,i); bf[t][1] = bld(WO,128,1,t,i); }
    const int c = i & 15;
    float bS[4], bT[4];
    #pragma unroll
    for (int t2 = 0; t2 < 4; ++t2){
      bS[t2] = bo[t2*16 + c];
      bT[t2] = bo[64 + t2*16 + c];
    }
    float xg[4][4], xn[4][4];
    __syncthreads();
    for (int J = 0; J <= NJ; ++J){
      const int t0 = SP*(J - lag);
      const int t0n = t0 + SP;
      if (t0n >= 0 && t0n < NT){
        #pragma unroll
        for (int t2 = 0; t2 < 4; ++t2){
          #pragma unroll
          for (int rg = 0; rg < 4; ++rg){
            const int t = t0n + 4*(i>>4) + rg;
            xn[t2][rg] = x[xbase + (long)t*NC + xoff + t2*16 + c];
          }
        }
      }
      if (t0 == 0){
        #pragma unroll
        for (int t2 = 0; t2 < 4; ++t2){
          #pragma unroll
          for (int rg = 0; rg < 4; ++rg){
            const int t = t0 + 4*(i>>4) + rg;
            xg[t2][rg] = x[xbase + (long)t*NC + xoff + t2*16 + c];
          }
        }
      }
      if (t0 >= 0 && t0 < NT){
        f16x8 a0 = ldafb(&hr[0][0], t0, i, 0);
        f16x8 a1 = ldafb(&hr[0][0], t0, i, 1);
        f32x4 zz = {0.f,0.f,0.f,0.f};
        f32x4 acc[8];
        #pragma unroll
        for (int t2 = 0; t2 < 8; ++t2){
          acc[t2] = zz;
          MFMA16(acc[t2], a0, bf[t2][0]);
          MFMA16(acc[t2], a1, bf[t2][1]);
        }
        #pragma unroll
        for (int t2 = 0; t2 < 4; ++t2){
          #pragma unroll
          for (int rg = 0; rg < 4; ++rg){
            const int t = t0 + 4*(i>>4) + rg;
            float y = e_func(acc[t2][rg] + bS[t2]) * xg[t2][rg] + (acc[t2+4][rg] + bT[t2]);
            out[xbase + (long)t*NC + xoff + t2*16 + c] = y;
            if (isB) y1p[t & (NSL-1)][t2*16 + c] = (_Float16)y;
          }
        }
      }
      #pragma unroll
      for (int t2 = 0; t2 < 4; ++t2)
        #pragma unroll
        for (int rg = 0; rg < 4; ++rg) xg[t2][rg] = xn[t2][rg];
      BAR();
    }
  }
}

extern "C" void kernel_launch(void* const* d_in, const int* in_sizes, int n_in,
                              void* d_out, int out_size, void* d_ws, size_t ws_size,
                              hipStream_t stream) {
  const float* x   = (const float*)d_in[0];
  const float* Wx1 = (const float*)d_in[1];
  const float* Wh1 = (const float*)d_in[2];
  const float* bx1 = (const float*)d_in[3];
  const float* bh1 = (const float*)d_in[4];
  const float* Wo1 = (const float*)d_in[5];
  const float* bo1 = (const float*)d_in[6];
  const float* Wx2 = (const float*)d_in[7];
  const float* Wh2 = (const float*)d_in[8];
  const float* bx2 = (const float*)d_in[9];
  const float* bh2 = (const float*)d_in[10];
  const float* Wo2 = (const float*)d_in[11];
  const float* bo2 = (const float*)d_in[12];
  float* out = (float*)d_out;

  hipLaunchKernelGGL(glow_gru_kernel, dim3(NB), dim3(384), 0, stream,
                     x, Wx1, Wh1, bx1, bh1, Wo1, bo1,
                     Wx2, Wh2, bx2, bh2, Wo2, bo2, out);
}